// Round 3
// baseline (75.248 us; speedup 1.0000x reference)
//
#include <hip/hip_runtime.h>

#define NB 32
#define TT 512
#define SS 5
#define CC 512
#define UU 256
#define NEGV -1e30f
#define LCH 16                 // timesteps per chunk
#define NCH (TT / LCH)         // 32 chunks
#define PKW 12                 // packed row width: e0..e3, b0..b4, pad x3

// ---------------------------------------------------------------------------
// Kernel A: per-row logsumexp over C=512. One wave64 per (n,t,s) row.
// Writes packed[t][n][12] = {em(s=0..3), bl(s=0..4)} for the scan stages.
// ---------------------------------------------------------------------------
__global__ __launch_bounds__(256) void row_lse_kernel(
    const float* __restrict__ logits,   // [N][T][S][C]
    const int*   __restrict__ ranges,   // [N][T][S]
    const int*   __restrict__ y,        // [N][U]
    float*       __restrict__ packed)   // [T][N][PKW]
{
    int row  = blockIdx.x * 4 + (threadIdx.x >> 6);   // 0 .. N*T*S-1
    int lane = threadIdx.x & 63;
    const float* rowp = logits + (size_t)row * CC;

    float4 v0 = *(const float4*)(rowp + lane * 8);
    float4 v1 = *(const float4*)(rowp + lane * 8 + 4);

    float m = fmaxf(fmaxf(fmaxf(v0.x, v0.y), fmaxf(v0.z, v0.w)),
                    fmaxf(fmaxf(v1.x, v1.y), fmaxf(v1.z, v1.w)));
#pragma unroll
    for (int off = 32; off; off >>= 1)
        m = fmaxf(m, __shfl_xor(m, off));

    float s = __expf(v0.x - m) + __expf(v0.y - m) +
              __expf(v0.z - m) + __expf(v0.w - m) +
              __expf(v1.x - m) + __expf(v1.y - m) +
              __expf(v1.z - m) + __expf(v1.w - m);
#pragma unroll
    for (int off = 32; off; off >>= 1)
        s += __shfl_xor(s, off);

    if (lane == 0) {
        float lse = m + __logf(s);
        int n    = row / (TT * SS);
        int rem  = row - n * (TT * SS);
        int t    = rem / SS;
        int sidx = rem - t * SS;
        int r    = ranges[row];          // lb + sidx
        int sym  = y[n * UU + r];
        float* dst = packed + ((size_t)t * NB + n) * PKW;
        if (sidx < 4) dst[sidx] = rowp[sym] - lse;   // em used only for s=0..3
        dst[4 + sidx] = rowp[0] - lse;               // bl for s=0..4
    }
}

// ---------------------------------------------------------------------------
// Semiring helpers. lse(x,y) = max + log1p(exp(-|x-y|)); max-semiring drops
// the correction. sel in {0,1} makes it branch-free for mixed-sem waves.
// ---------------------------------------------------------------------------
__device__ __forceinline__ float lse_corr(float x, float y) {
    return __logf(1.0f + __expf(-fabsf(x - y)));
}
__device__ __forceinline__ float combsel(float x, float y, float sel) {
    return fmaxf(x, y) + sel * lse_corr(x, y);
}
template <bool MAXSEM>
__device__ __forceinline__ float combf(float x, float y) {
    return MAXSEM ? fmaxf(x, y) : fmaxf(x, y) + lse_corr(x, y);
}

// ---------------------------------------------------------------------------
// Stage 1: chunk -> 5x5 semiring matrix, columns in parallel.
// grid = NCH blocks; block = (64, 5): lane = n + 32*sem, y = basis column j.
// All chunk data staged in LDS first (bulk coalesced loads).
// mats layout: [sem][c][n][25], entry j*5+s = F_c(e_j)[s].
// ---------------------------------------------------------------------------
__global__ __launch_bounds__(320) void scan_stage1(
    const float* __restrict__ packed,   // [T][N][PKW]
    const int*   __restrict__ ranges,   // [N][T][S]
    float*       __restrict__ mats)
{
    __shared__ float pk[LCH][NB][PKW];      // 24 KB
    __shared__ int   lbb[LCH + 1][NB];      // 2.1 KB

    int tid = threadIdx.y * 64 + threadIdx.x;   // 0..319
    int c   = blockIdx.x;
    int t0  = c * LCH;

    // --- bulk load packed chunk (1536 float4), 4 rounds + 1 guarded ---
    {
        const float4* gsrc = (const float4*)(packed + (size_t)t0 * NB * PKW);
        float4* ldst = (float4*)&pk[0][0][0];
        float4 a0 = gsrc[tid];
        float4 a1 = gsrc[tid + 320];
        float4 a2 = gsrc[tid + 640];
        float4 a3 = gsrc[tid + 960];
        bool g4 = (tid + 1280) < LCH * NB * 3;
        float4 a4 = g4 ? gsrc[tid + 1280] : a0;
        ldst[tid] = a0; ldst[tid + 320] = a1; ldst[tid + 640] = a2;
        ldst[tid + 960] = a3;
        if (g4) ldst[tid + 1280] = a4;
    }
    // --- lb values for shift flags: (LCH+1)*NB = 544 ints ---
    {
        int i0 = tid;
        int ii = i0 >> 5, n = i0 & 31;
        int t = t0 + ii; if (t > TT - 1) t = TT - 1;
        int vA = ranges[(n * TT + t) * SS];
        int i1 = tid + 320;
        int vB = 0;
        bool g1 = i1 < (LCH + 1) * NB;
        if (g1) {
            int ii1 = i1 >> 5, n1 = i1 & 31;
            int t1 = t0 + ii1; if (t1 > TT - 1) t1 = TT - 1;
            vB = ranges[(n1 * TT + t1) * SS];
        }
        lbb[ii][n] = vA;
        if (g1) lbb[i1 >> 5][i1 & 31] = vB;
    }
    __syncthreads();

    int lane = threadIdx.x;         // 0..63
    int n    = lane & 31;
    int sem  = lane >> 5;           // 0 = lse, 1 = max
    float sel = sem ? 0.0f : 1.0f;
    int j    = threadIdx.y;

    float v0 = (j == 0) ? 0.0f : NEGV;
    float v1 = (j == 1) ? 0.0f : NEGV;
    float v2 = (j == 2) ? 0.0f : NEGV;
    float v3 = (j == 3) ? 0.0f : NEGV;
    float v4 = (j == 4) ? 0.0f : NEGV;

    for (int i = 0; i < LCH; ++i) {
        int t = t0 + i;
        float e0 = pk[i][n][0], e1 = pk[i][n][1];
        float e2 = pk[i][n][2], e3 = pk[i][n][3];

        v1 = combsel(v1, v0 + e0, sel);
        v2 = combsel(v2, v1 + e1, sel);
        v3 = combsel(v3, v2 + e2, sel);
        v4 = combsel(v4, v3 + e3, sel);

        if (t < TT - 1) {                        // wave-uniform
            float b0 = pk[i][n][4], b1 = pk[i][n][5], b2 = pk[i][n][6];
            float b3 = pk[i][n][7], b4 = pk[i][n][8];
            bool sh = lbb[i + 1][n] != lbb[i][n];    // delta in {0,1}
            float n0 = sh ? v1 + b1 : v0 + b0;
            float n1 = sh ? v2 + b2 : v1 + b1;
            float n2 = sh ? v3 + b3 : v2 + b2;
            float n3 = sh ? v4 + b4 : v3 + b3;
            float n4 = sh ? NEGV    : v4 + b4;
            v0 = n0; v1 = n1; v2 = n2; v3 = n3; v4 = n4;
        }
    }

    float* outp = mats + (((size_t)sem * NCH + c) * NB + n) * 25 + j * 5;
    outp[0] = v0; outp[1] = v1; outp[2] = v2; outp[3] = v3; outp[4] = v4;
}

// ---------------------------------------------------------------------------
// Stage 2: compose the 32 chunk matrices per (n, sem) as serial matvecs.
// One block per semiring; 512 threads cooperatively stage 16 matrices
// (54 KB, stride-27 padded -> conflict-free) into LDS per half; wave 0
// runs the serial chain from LDS with register double-buffering.
// ---------------------------------------------------------------------------
#define HCH (NCH / 2)                 // 16 chunks per half
#define MLW 27                        // padded matrix row width in LDS

template <bool MAXSEM>
__device__ __forceinline__ void matvec(const float m[25],
    float& v0, float& v1, float& v2, float& v3, float& v4)
{
    float r0 = combf<MAXSEM>(combf<MAXSEM>(combf<MAXSEM>(combf<MAXSEM>(
                 m[0] + v0, m[5] + v1), m[10] + v2), m[15] + v3), m[20] + v4);
    float r1 = combf<MAXSEM>(combf<MAXSEM>(combf<MAXSEM>(combf<MAXSEM>(
                 m[1] + v0, m[6] + v1), m[11] + v2), m[16] + v3), m[21] + v4);
    float r2 = combf<MAXSEM>(combf<MAXSEM>(combf<MAXSEM>(combf<MAXSEM>(
                 m[2] + v0, m[7] + v1), m[12] + v2), m[17] + v3), m[22] + v4);
    float r3 = combf<MAXSEM>(combf<MAXSEM>(combf<MAXSEM>(combf<MAXSEM>(
                 m[3] + v0, m[8] + v1), m[13] + v2), m[18] + v3), m[23] + v4);
    float r4 = combf<MAXSEM>(combf<MAXSEM>(combf<MAXSEM>(combf<MAXSEM>(
                 m[4] + v0, m[9] + v1), m[14] + v2), m[19] + v3), m[24] + v4);
    v0 = r0; v1 = r1; v2 = r2; v3 = r3; v4 = r4;
}

template <bool MAXSEM>
__device__ __forceinline__ void compose_run(
    const float* __restrict__ g,     // [NCH][NB][25] for this sem
    float* __restrict__ ml,          // LDS [HCH][NB][MLW]
    float* __restrict__ out, int sem)
{
    float v0 = 0.0f, v1 = NEGV, v2 = NEGV, v3 = NEGV, v4 = NEGV;
    int lane = threadIdx.x & 63;
    bool w0  = threadIdx.x < 64;
    bool active = w0 && lane < NB;
    int n = lane & 31;

    for (int half = 0; half < 2; ++half) {
        __syncthreads();   // previous half fully consumed
        // stage 16 matrices: 12800 floats, 25 uniform rounds of 512
#pragma unroll 5
        for (int r = 0; r < 25; ++r) {
            int fl = r * 512 + threadIdx.x;
            int cn = fl / 25;                 // c_local*NB + n
            int k  = fl - cn * 25;
            ml[cn * MLW + k] = g[half * (HCH * NB * 25) + fl];
        }
        __syncthreads();

        if (w0) {
            const float* base = ml + n * MLW;    // c_local stride = NB*MLW
            float mA[25], mB[25];
#pragma unroll
            for (int k = 0; k < 25; ++k) mA[k] = base[k];
            for (int c = 0; c < HCH; c += 2) {
#pragma unroll
                for (int k = 0; k < 25; ++k)
                    mB[k] = base[(c + 1) * (NB * MLW) + k];
                matvec<MAXSEM>(mA, v0, v1, v2, v3, v4);
                if (c + 2 < HCH) {
#pragma unroll
                    for (int k = 0; k < 25; ++k)
                        mA[k] = base[(c + 2) * (NB * MLW) + k];
                }
                matvec<MAXSEM>(mB, v0, v1, v2, v3, v4);
            }
        }
    }

    if (w0) {
        float p = active ? -v4 : 0.0f;
#pragma unroll
        for (int off = 16; off; off >>= 1)
            p += __shfl_xor(p, off);
        if (lane == 0) out[sem] = p;
    }
}

__global__ __launch_bounds__(512) void scan_stage2(
    const float* __restrict__ mats, float* __restrict__ out)
{
    __shared__ float ml[HCH * NB * MLW];     // 54 KB
    int sem = blockIdx.x;
    const float* g = mats + (size_t)sem * NCH * NB * 25;
    if (sem == 0) compose_run<false>(g, ml, out, 0);
    else          compose_run<true >(g, ml, out, 1);
}

extern "C" void kernel_launch(void* const* d_in, const int* in_sizes, int n_in,
                              void* d_out, int out_size, void* d_ws, size_t ws_size,
                              hipStream_t stream) {
    const float* logits = (const float*)d_in[0];
    const int*   ranges = (const int*)d_in[1];
    const int*   y      = (const int*)d_in[2];
    // d_in[3] = x_lens, unused (reference ignores it; all == T)

    float* packed = (float*)d_ws;                       // T*N*12 floats
    float* mats   = packed + (size_t)TT * NB * PKW;     // 2*NCH*NB*25 floats
    float* out    = (float*)d_out;

    int rows = NB * TT * SS;                            // 81920
    hipLaunchKernelGGL(row_lse_kernel, dim3(rows / 4), dim3(256), 0, stream,
                       logits, ranges, y, packed);
    hipLaunchKernelGGL(scan_stage1, dim3(NCH), dim3(64, 5), 0, stream,
                       packed, ranges, mats);
    hipLaunchKernelGGL(scan_stage2, dim3(2), dim3(512), 0, stream,
                       mats, out);
}